// Round 4
// baseline (675.374 us; speedup 1.0000x reference)
//
#include <hip/hip_runtime.h>
#include <hip/hip_cooperative_groups.h>
#include <math.h>

namespace cg = cooperative_groups;

#define HDIM 300
#define LBL  5
#define NBLK 256
#define NTHR 1024

__device__ __forceinline__ float sigmoidf_(float x) {
    return 1.0f / (1.0f + expf(-x));
}

// ---------------------------------------------------------------------------
// One cooperative kernel for the whole tree:
//   phase P (proj):  ixx/fxx/uxx = emb[word]@W_*x + b_*x for all nodes,
//                    fused leaf cells (hsum = 0) straight from LDS.
//   phase L (x9):    one block per node of the level; 3 matvecs vs W_ih/W_fh/W_uh
//                    with child h staged in LDS; cell update. grid.sync between.
//   phase O (out):   logits -> log_softmax -> loss.
// 256 blocks x 1024 threads, co-resident (1 block/CU, ~19.2 KB LDS).
// ---------------------------------------------------------------------------
__global__ __launch_bounds__(NTHR)
void tree_lstm_kernel(const int* __restrict__ word_ids,
                      const int* __restrict__ labels,
                      const int* __restrict__ children_idx,
                      const int* __restrict__ children_mask,
                      const float* __restrict__ emb,
                      const float* __restrict__ W_ix, const float* __restrict__ b_ix,
                      const float* __restrict__ W_ih, const float* __restrict__ b_ih,
                      const float* __restrict__ W_fx, const float* __restrict__ b_fx,
                      const float* __restrict__ W_fh, const float* __restrict__ b_fh,
                      const float* __restrict__ W_ux, const float* __restrict__ b_ux,
                      const float* __restrict__ W_uh, const float* __restrict__ b_uh,
                      const float* __restrict__ W_out, const float* __restrict__ b_out,
                      float* __restrict__ ixx, float* __restrict__ fxx,
                      float* __restrict__ uxx,
                      float* __restrict__ c_all, float* __restrict__ h_all,
                      float* __restrict__ out, float* __restrict__ loss,
                      int N)
{
    cg::grid_group grid = cg::this_grid();

    __shared__ union {
        struct { float x[4][HDIM]; float li[4][HDIM]; float lf[4][HDIM]; float lu[4][HDIM]; } p;
        struct { float h0[HDIM]; float h1[HDIM]; float aih[HDIM]; float g0[HDIM]; float g1[HDIM]; float auh[HDIM]; } l;
        struct { float part[4][4][LBL]; } o;
    } sm;

    const int b   = blockIdx.x;
    const int tid = threadIdx.x;
    const int leaves = (N + 1) / 2;
    const int t0 = b * 4;

    // ---------------- phase P: projections + leaf cells ----------------
    for (int idx = tid; idx < 4 * HDIM; idx += NTHR) {
        int r = idx / HDIM, i = idx - r * HDIM;
        int t = t0 + r;
        float v = 0.f;
        if (t < N) v = emb[(size_t)word_ids[t] * HDIM + i];
        sm.p.x[r][i] = v;
    }
    __syncthreads();

    if (tid < 3 * HDIM) {
        const int mat = tid / HDIM;
        const int j   = tid - mat * HDIM;
        const float* __restrict__ W = (mat == 0) ? W_ix : (mat == 1) ? W_fx : W_ux;
        const float* __restrict__ B = (mat == 0) ? b_ix : (mat == 1) ? b_fx : b_ux;
        float* __restrict__ O       = (mat == 0) ? ixx  : (mat == 1) ? fxx  : uxx;
        float (* __restrict__ L)[HDIM] = (mat == 0) ? sm.p.li : (mat == 1) ? sm.p.lf : sm.p.lu;

        float a0 = 0.f, a1 = 0.f, a2 = 0.f, a3 = 0.f;
#pragma unroll 6
        for (int i = 0; i < HDIM; i++) {
            float w = W[i * HDIM + j];
            a0 = fmaf(sm.p.x[0][i], w, a0);
            a1 = fmaf(sm.p.x[1][i], w, a1);
            a2 = fmaf(sm.p.x[2][i], w, a2);
            a3 = fmaf(sm.p.x[3][i], w, a3);
        }
        const float bb = B[j];
        float v[4] = { a0 + bb, a1 + bb, a2 + bb, a3 + bb };
#pragma unroll
        for (int r = 0; r < 4; r++) {
            int t = t0 + r;
            if (t < N) O[(size_t)t * HDIM + j] = v[r];
            L[r][j] = v[r];
        }
    }
    __syncthreads();

    if (tid < HDIM) {
        const int j = tid;
        const float bih = b_ih[j], bfh = b_fh[j], buh = b_uh[j];
#pragma unroll
        for (int r = 0; r < 4; r++) {
            int t = t0 + r;
            if (t < leaves && t < N) {
                float ig = sigmoidf_(sm.p.li[r][j] + bih);
                float og = sigmoidf_(sm.p.lf[r][j] + bfh);
                float ug = sigmoidf_(sm.p.lu[r][j] + buh);
                float c = ig * ug;
                float h = og * tanhf(c);
                c_all[(size_t)t * HDIM + j] = c;
                h_all[(size_t)t * HDIM + j] = h;
            }
        }
    }
    if (b == 0 && tid == 0) *loss = 0.f;

    grid.sync();

    // ---------------- phase L: 9 levels, block-per-node ----------------
    int prev = leaves, start = leaves;
    while (prev > 1) {
        int size = prev / 2;
        if (b < size) {
            const int t  = start + b;
            const int c0 = children_idx[2 * t];
            const int c1 = children_idx[2 * t + 1];
            const float m0 = (float)children_mask[2 * t];
            const float m1 = (float)children_mask[2 * t + 1];

            if (tid < 2 * HDIM) {
                int r = (tid < HDIM) ? 0 : 1;
                int i = tid - r * HDIM;
                int ch = r ? c1 : c0;
                float m = r ? m1 : m0;
                float hv = h_all[(size_t)ch * HDIM + i] * m;
                if (r) sm.l.h1[i] = hv; else sm.l.h0[i] = hv;
            }
            __syncthreads();

            if (tid < 3 * HDIM) {
                const int g = tid / HDIM;
                const int j = tid - g * HDIM;
                if (g == 1) {
                    float a0 = 0.f, a1 = 0.f;
#pragma unroll 6
                    for (int i = 0; i < HDIM; i++) {
                        float w = W_fh[i * HDIM + j];
                        a0 = fmaf(sm.l.h0[i], w, a0);
                        a1 = fmaf(sm.l.h1[i], w, a1);
                    }
                    sm.l.g0[j] = a0;
                    sm.l.g1[j] = a1;
                } else {
                    const float* __restrict__ W = (g == 0) ? W_ih : W_uh;
                    float a = 0.f;
#pragma unroll 6
                    for (int i = 0; i < HDIM; i++) {
                        float w = W[i * HDIM + j];
                        a = fmaf(sm.l.h0[i] + sm.l.h1[i], w, a);
                    }
                    if (g == 0) sm.l.aih[j] = a; else sm.l.auh[j] = a;
                }
            }
            __syncthreads();

            if (tid < HDIM) {
                const int j = tid;
                size_t o = (size_t)t * HDIM + j;
                float vix = ixx[o], vfx = fxx[o], vux = uxx[o];
                float g0 = sm.l.g0[j], g1 = sm.l.g1[j];
                float bfh = b_fh[j];
                float ig = sigmoidf_(vix + sm.l.aih[j] + b_ih[j]);
                float og = sigmoidf_(vfx + g0 + g1 + bfh);
                float ug = sigmoidf_(vux + sm.l.auh[j] + b_uh[j]);
                float f0 = sigmoidf_(g0 + bfh + vfx);
                float f1 = sigmoidf_(g1 + bfh + vfx);
                float cc0 = c_all[(size_t)c0 * HDIM + j] * m0;
                float cc1 = c_all[(size_t)c1 * HDIM + j] * m1;
                float c = ig * ug + f0 * cc0 + f1 * cc1;
                float h = og * tanhf(c);
                c_all[o] = c;
                h_all[o] = h;
            }
        }
        grid.sync();
        prev = size;
        start += size;
    }

    // ---------------- phase O: output head ----------------
    {
        const int r  = tid >> 8;          // node slot 0..3
        const int k2 = tid & 255;         // 256-thread K partition
        const int t  = t0 + r;

        float acc[LBL];
#pragma unroll
        for (int k = 0; k < LBL; k++) acc[k] = 0.f;

        if (t < N) {
            for (int i = k2; i < HDIM; i += 256) {
                float hv = h_all[(size_t)t * HDIM + i];
#pragma unroll
                for (int k = 0; k < LBL; k++)
                    acc[k] = fmaf(hv, W_out[i * LBL + k], acc[k]);
            }
        }
#pragma unroll
        for (int k = 0; k < LBL; k++) {
            float v = acc[k];
            for (int off = 32; off > 0; off >>= 1)
                v += __shfl_down(v, off, 64);
            acc[k] = v;
        }
        const int lane = tid & 63;
        const int w4   = (tid >> 6) & 3;
        if (lane == 0) {
#pragma unroll
            for (int k = 0; k < LBL; k++) sm.o.part[r][w4][k] = acc[k];
        }
        __syncthreads();

        if (tid < 4) {
            int tt = t0 + tid;
            if (tt < N) {
                float lg[LBL];
                float mx = -1e30f;
#pragma unroll
                for (int k = 0; k < LBL; k++) {
                    lg[k] = sm.o.part[tid][0][k] + sm.o.part[tid][1][k] +
                            sm.o.part[tid][2][k] + sm.o.part[tid][3][k] + b_out[k];
                    mx = fmaxf(mx, lg[k]);
                }
                float s = 0.f;
#pragma unroll
                for (int k = 0; k < LBL; k++) s += expf(lg[k] - mx);
                float lse = mx + logf(s);
                int lab = labels[tt];
#pragma unroll
                for (int k = 0; k < LBL; k++)
                    out[tt * LBL + k] = lg[k] - lse;
                atomicAdd(loss, -(lg[lab] - lse));
            }
        }
    }
}

// ---------------------------------------------------------------------------
extern "C" void kernel_launch(void* const* d_in, const int* in_sizes, int n_in,
                              void* d_out, int out_size, void* d_ws, size_t ws_size,
                              hipStream_t stream)
{
    const int*   word_ids      = (const int*)d_in[0];
    const int*   labels        = (const int*)d_in[1];
    const int*   children_idx  = (const int*)d_in[2];
    const int*   children_mask = (const int*)d_in[3];
    const float* emb   = (const float*)d_in[4];
    const float* W_ix  = (const float*)d_in[5];  const float* b_ix = (const float*)d_in[6];
    const float* W_ih  = (const float*)d_in[7];  const float* b_ih = (const float*)d_in[8];
    const float* W_fx  = (const float*)d_in[9];  const float* b_fx = (const float*)d_in[10];
    const float* W_fh  = (const float*)d_in[11]; const float* b_fh = (const float*)d_in[12];
    const float* W_ux  = (const float*)d_in[13]; const float* b_ux = (const float*)d_in[14];
    const float* W_uh  = (const float*)d_in[15]; const float* b_uh = (const float*)d_in[16];
    const float* W_out = (const float*)d_in[17]; const float* b_out = (const float*)d_in[18];

    const int N = in_sizes[0];

    float* out  = (float*)d_out;
    float* loss = out + (size_t)N * LBL;

    float* ws    = (float*)d_ws;
    float* ixx   = ws;
    float* fxx   = ixx + (size_t)N * HDIM;
    float* uxx   = fxx + (size_t)N * HDIM;
    float* c_all = uxx + (size_t)N * HDIM;
    float* h_all = c_all + (size_t)N * HDIM;

    int Nv = N;
    void* args[] = {
        (void*)&word_ids, (void*)&labels, (void*)&children_idx, (void*)&children_mask,
        (void*)&emb,
        (void*)&W_ix, (void*)&b_ix, (void*)&W_ih, (void*)&b_ih,
        (void*)&W_fx, (void*)&b_fx, (void*)&W_fh, (void*)&b_fh,
        (void*)&W_ux, (void*)&b_ux, (void*)&W_uh, (void*)&b_uh,
        (void*)&W_out, (void*)&b_out,
        (void*)&ixx, (void*)&fxx, (void*)&uxx, (void*)&c_all, (void*)&h_all,
        (void*)&out, (void*)&loss, (void*)&Nv
    };
    hipLaunchCooperativeKernel((const void*)tree_lstm_kernel,
                               dim3(NBLK), dim3(NTHR), args, 0, stream);
}

// Round 5
// 633.571 us; speedup vs baseline: 1.0660x; 1.0660x over previous
//
#include <hip/hip_runtime.h>
#include <hip/hip_cooperative_groups.h>
#include <math.h>

namespace cg = cooperative_groups;

#define HDIM 300
#define KH   150    // K-half
#define JP   150    // column pairs
#define LBL  5
#define NBLK 256
#define NTHR 1024

__device__ __forceinline__ float sigmoidf_(float x) {
    return 1.0f / (1.0f + expf(-x));
}

// ---------------------------------------------------------------------------
// Single cooperative kernel. Matvec threads: (mat g, col-pair j2, K-half kh),
// groups padded to 320 threads (5 waves) so each wave is mat-uniform.
// Each thread: 150 float2 weight loads, 2-4 independent accumulators.
// Partial sums (per K-half) combined through LDS.
// ---------------------------------------------------------------------------
__global__ __launch_bounds__(NTHR, 4)
void tree_lstm_kernel(const int* __restrict__ word_ids,
                      const int* __restrict__ labels,
                      const int* __restrict__ children_idx,
                      const int* __restrict__ children_mask,
                      const float* __restrict__ emb,
                      const float* __restrict__ W_ix, const float* __restrict__ b_ix,
                      const float* __restrict__ W_ih, const float* __restrict__ b_ih,
                      const float* __restrict__ W_fx, const float* __restrict__ b_fx,
                      const float* __restrict__ W_fh, const float* __restrict__ b_fh,
                      const float* __restrict__ W_ux, const float* __restrict__ b_ux,
                      const float* __restrict__ W_uh, const float* __restrict__ b_uh,
                      const float* __restrict__ W_out, const float* __restrict__ b_out,
                      float* __restrict__ ixx, float* __restrict__ fxx,
                      float* __restrict__ uxx,
                      float* __restrict__ c_all, float* __restrict__ h_all,
                      float* __restrict__ out, float* __restrict__ loss,
                      int N)
{
    cg::grid_group grid = cg::this_grid();

    __shared__ union {
        struct {                       // proj phase
            float  x[4][HDIM];         // 4 embedding rows
            float2 pp[3][2][4][JP];    // [mat][khalf][node][colpair] partials
            float2 lc[3][4][JP];       // combined projections (for leaf cells)
        } p;
        struct {                       // level phase
            float  h0[HDIM], h1[HDIM];
            float2 pg0[2][JP], pg1[2][JP], pa0[2][JP], pa2[2][JP];
        } l;
        struct { float part[4][4][LBL]; } o;
    } sm;
    __shared__ float rooth[HDIM];

    const int b   = blockIdx.x;
    const int tid = threadIdx.x;
    const int leaves = (N + 1) / 2;
    const int t0 = b * 4;

    // matvec thread decomposition (group = 320 threads = 5 waves, mat-uniform)
    const int g    = tid / 320;            // 0..2 (tid<960), 3 = idle tail
    const int rem  = tid - g * 320;
    const bool act = (tid < 960) && (rem < 2 * KH);
    const int kh   = rem / KH;             // K-half
    const int j2   = rem - kh * KH;        // column pair
    const int i0   = kh * KH;

    // ================= phase P: x-projections + leaf cells =================
    for (int idx = tid; idx < 4 * HDIM; idx += NTHR) {
        int r = idx / HDIM, i = idx - r * HDIM;
        int t = t0 + r;
        float v = 0.f;
        if (t < N) v = emb[(size_t)word_ids[t] * HDIM + i];
        sm.p.x[r][i] = v;
    }
    if (b == 0 && tid == 0) *loss = 0.f;
    __syncthreads();

    if (act) {
        const float* __restrict__ W = (g == 0) ? W_ix : (g == 1) ? W_fx : W_ux;
        const float* __restrict__ Wp = W + (size_t)i0 * HDIM + 2 * j2;
        float2 a0 = {0,0}, a1 = {0,0}, a2 = {0,0}, a3 = {0,0};
#pragma unroll 6
        for (int i = 0; i < KH; i++) {
            float2 w = *(const float2*)(Wp + (size_t)i * HDIM);
            float x0 = sm.p.x[0][i0 + i];
            float x1 = sm.p.x[1][i0 + i];
            float x2 = sm.p.x[2][i0 + i];
            float x3 = sm.p.x[3][i0 + i];
            a0.x = fmaf(x0, w.x, a0.x); a0.y = fmaf(x0, w.y, a0.y);
            a1.x = fmaf(x1, w.x, a1.x); a1.y = fmaf(x1, w.y, a1.y);
            a2.x = fmaf(x2, w.x, a2.x); a2.y = fmaf(x2, w.y, a2.y);
            a3.x = fmaf(x3, w.x, a3.x); a3.y = fmaf(x3, w.y, a3.y);
        }
        sm.p.pp[g][kh][0][j2] = a0;
        sm.p.pp[g][kh][1][j2] = a1;
        sm.p.pp[g][kh][2][j2] = a2;
        sm.p.pp[g][kh][3][j2] = a3;
    }
    __syncthreads();

    if (tid < 3 * JP) {                    // combine K-halves, add bias, store
        const int gg = tid / JP;
        const int jj = tid - gg * JP;
        const float* __restrict__ B = (gg == 0) ? b_ix : (gg == 1) ? b_fx : b_ux;
        float* __restrict__ O       = (gg == 0) ? ixx  : (gg == 1) ? fxx  : uxx;
        float2 bb = *(const float2*)(B + 2 * jj);
#pragma unroll
        for (int r = 0; r < 4; r++) {
            float2 v;
            v.x = sm.p.pp[gg][0][r][jj].x + sm.p.pp[gg][1][r][jj].x + bb.x;
            v.y = sm.p.pp[gg][0][r][jj].y + sm.p.pp[gg][1][r][jj].y + bb.y;
            int t = t0 + r;
            if (t < N) *(float2*)(O + (size_t)t * HDIM + 2 * jj) = v;
            sm.p.lc[gg][r][jj] = v;
        }
    }
    __syncthreads();

    if (tid < HDIM) {                      // leaf cells (hsum = 0)
        const int j = tid;
        const float bih = b_ih[j], bfh = b_fh[j], buh = b_uh[j];
        const float* LI = (const float*)sm.p.lc[0];
        const float* LF = (const float*)sm.p.lc[1];
        const float* LU = (const float*)sm.p.lc[2];
#pragma unroll
        for (int r = 0; r < 4; r++) {
            int t = t0 + r;
            if (t < leaves && t < N) {
                float ig = sigmoidf_(LI[r * HDIM + j] + bih);
                float og = sigmoidf_(LF[r * HDIM + j] + bfh);
                float ug = sigmoidf_(LU[r * HDIM + j] + buh);
                float c = ig * ug;
                float h = og * tanhf(c);
                c_all[(size_t)t * HDIM + j] = c;
                h_all[(size_t)t * HDIM + j] = h;
            }
        }
    }
    grid.sync();

    // ================= phase L: 9 levels =================
    int prev = leaves, start = leaves;
    while (prev > 1) {
        int size = prev / 2;
        if (b < size) {
            const int t  = start + b;
            const int c0 = children_idx[2 * t];
            const int c1 = children_idx[2 * t + 1];
            const float m0 = (float)children_mask[2 * t];
            const float m1 = (float)children_mask[2 * t + 1];

            if (tid < 2 * HDIM) {
                int r = (tid < HDIM) ? 0 : 1;
                int i = tid - r * HDIM;
                int ch = r ? c1 : c0;
                float m = r ? m1 : m0;
                float hv = h_all[(size_t)ch * HDIM + i] * m;
                if (r) sm.l.h1[i] = hv; else sm.l.h0[i] = hv;
            }
            __syncthreads();

            if (act) {
                if (g == 1) {              // W_fh: separate h0/h1 accumulators
                    const float* __restrict__ Wp = W_fh + (size_t)i0 * HDIM + 2 * j2;
                    float2 A = {0,0}, C = {0,0};
#pragma unroll 6
                    for (int i = 0; i < KH; i++) {
                        float2 w = *(const float2*)(Wp + (size_t)i * HDIM);
                        float h0v = sm.l.h0[i0 + i];
                        float h1v = sm.l.h1[i0 + i];
                        A.x = fmaf(h0v, w.x, A.x); A.y = fmaf(h0v, w.y, A.y);
                        C.x = fmaf(h1v, w.x, C.x); C.y = fmaf(h1v, w.y, C.y);
                    }
                    sm.l.pg0[kh][j2] = A;
                    sm.l.pg1[kh][j2] = C;
                } else {                   // W_ih / W_uh on hsum
                    const float* __restrict__ W = (g == 0) ? W_ih : W_uh;
                    const float* __restrict__ Wp = W + (size_t)i0 * HDIM + 2 * j2;
                    float2 A = {0,0};
#pragma unroll 6
                    for (int i = 0; i < KH; i++) {
                        float2 w = *(const float2*)(Wp + (size_t)i * HDIM);
                        float hs = sm.l.h0[i0 + i] + sm.l.h1[i0 + i];
                        A.x = fmaf(hs, w.x, A.x); A.y = fmaf(hs, w.y, A.y);
                    }
                    if (g == 0) sm.l.pa0[kh][j2] = A;
                    else        sm.l.pa2[kh][j2] = A;
                }
            }
            __syncthreads();

            if (tid < HDIM) {              // cell update
                const int j = tid;
                const float* G0 = (const float*)sm.l.pg0;
                const float* G1 = (const float*)sm.l.pg1;
                const float* A0 = (const float*)sm.l.pa0;
                const float* A2 = (const float*)sm.l.pa2;
                float gg0 = G0[j] + G0[HDIM + j];
                float gg1 = G1[j] + G1[HDIM + j];
                float aih = A0[j] + A0[HDIM + j];
                float auh = A2[j] + A2[HDIM + j];
                size_t o = (size_t)t * HDIM + j;
                float vix = ixx[o], vfx = fxx[o], vux = uxx[o];
                float bfh = b_fh[j];
                float ig = sigmoidf_(vix + aih + b_ih[j]);
                float og = sigmoidf_(vfx + gg0 + gg1 + bfh);
                float ug = sigmoidf_(vux + auh + b_uh[j]);
                float f0 = sigmoidf_(gg0 + bfh + vfx);
                float f1 = sigmoidf_(gg1 + bfh + vfx);
                float cc0 = c_all[(size_t)c0 * HDIM + j] * m0;
                float cc1 = c_all[(size_t)c1 * HDIM + j] * m1;
                float c = ig * ug + f0 * cc0 + f1 * cc1;
                float h = og * tanhf(c);
                c_all[o] = c;
                h_all[o] = h;
                if (size == 1) rooth[j] = h;   // root h stays on-chip
            }
        }
        if (size > 1) grid.sync();         // no grid sync after the root level
        prev = size;
        start += size;
    }
    __syncthreads();                       // protect sm union reuse (block 0)

    // ================= phase O: output head =================
    {
        const int r  = tid >> 8;
        const int k2 = tid & 255;
        const int t  = t0 + r;

        float acc[LBL];
#pragma unroll
        for (int k = 0; k < LBL; k++) acc[k] = 0.f;

        if (t < N - 1) {                   // root (t == N-1) handled by block 0
            for (int i = k2; i < HDIM; i += 256) {
                float hv = h_all[(size_t)t * HDIM + i];
#pragma unroll
                for (int k = 0; k < LBL; k++)
                    acc[k] = fmaf(hv, W_out[i * LBL + k], acc[k]);
            }
        }
#pragma unroll
        for (int k = 0; k < LBL; k++) {
            float v = acc[k];
            for (int off = 32; off > 0; off >>= 1)
                v += __shfl_down(v, off, 64);
            acc[k] = v;
        }
        const int lane = tid & 63;
        const int w4   = (tid >> 6) & 3;
        if (lane == 0) {
#pragma unroll
            for (int k = 0; k < LBL; k++) sm.o.part[r][w4][k] = acc[k];
        }
        __syncthreads();

        if (tid < 4) {
            int tt = t0 + tid;
            if (tt < N - 1) {
                float lg[LBL];
                float mx = -1e30f;
#pragma unroll
                for (int k = 0; k < LBL; k++) {
                    lg[k] = sm.o.part[tid][0][k] + sm.o.part[tid][1][k] +
                            sm.o.part[tid][2][k] + sm.o.part[tid][3][k] + b_out[k];
                    mx = fmaxf(mx, lg[k]);
                }
                float s = 0.f;
#pragma unroll
                for (int k = 0; k < LBL; k++) s += expf(lg[k] - mx);
                float lse = mx + logf(s);
                int lab = labels[tt];
#pragma unroll
                for (int k = 0; k < LBL; k++)
                    out[tt * LBL + k] = lg[k] - lse;
                atomicAdd(loss, -(lg[lab] - lse));
            }
        }
    }

    // root output row (block 0 only; root h is in LDS)
    if (b == 0) {
        __syncthreads();
        float acc[LBL];
#pragma unroll
        for (int k = 0; k < LBL; k++) acc[k] = 0.f;
        if (tid < 256) {
            for (int i = tid; i < HDIM; i += 256) {
                float hv = rooth[i];
#pragma unroll
                for (int k = 0; k < LBL; k++)
                    acc[k] = fmaf(hv, W_out[i * LBL + k], acc[k]);
            }
#pragma unroll
            for (int k = 0; k < LBL; k++) {
                float v = acc[k];
                for (int off = 32; off > 0; off >>= 1)
                    v += __shfl_down(v, off, 64);
                acc[k] = v;
            }
            const int lane = tid & 63;
            const int w4   = tid >> 6;
            if (lane == 0) {
#pragma unroll
                for (int k = 0; k < LBL; k++) sm.o.part[0][w4][k] = acc[k];
            }
        }
        __syncthreads();
        if (tid == 0) {
            float lg[LBL];
            float mx = -1e30f;
#pragma unroll
            for (int k = 0; k < LBL; k++) {
                lg[k] = sm.o.part[0][0][k] + sm.o.part[0][1][k] +
                        sm.o.part[0][2][k] + sm.o.part[0][3][k] + b_out[k];
                mx = fmaxf(mx, lg[k]);
            }
            float s = 0.f;
#pragma unroll
            for (int k = 0; k < LBL; k++) s += expf(lg[k] - mx);
            float lse = mx + logf(s);
            int lab = labels[N - 1];
#pragma unroll
            for (int k = 0; k < LBL; k++)
                out[(N - 1) * LBL + k] = lg[k] - lse;
            atomicAdd(loss, -(lg[lab] - lse));
        }
    }
}

// ---------------------------------------------------------------------------
extern "C" void kernel_launch(void* const* d_in, const int* in_sizes, int n_in,
                              void* d_out, int out_size, void* d_ws, size_t ws_size,
                              hipStream_t stream)
{
    const int*   word_ids      = (const int*)d_in[0];
    const int*   labels        = (const int*)d_in[1];
    const int*   children_idx  = (const int*)d_in[2];
    const int*   children_mask = (const int*)d_in[3];
    const float* emb   = (const float*)d_in[4];
    const float* W_ix  = (const float*)d_in[5];  const float* b_ix = (const float*)d_in[6];
    const float* W_ih  = (const float*)d_in[7];  const float* b_ih = (const float*)d_in[8];
    const float* W_fx  = (const float*)d_in[9];  const float* b_fx = (const float*)d_in[10];
    const float* W_fh  = (const float*)d_in[11]; const float* b_fh = (const float*)d_in[12];
    const float* W_ux  = (const float*)d_in[13]; const float* b_ux = (const float*)d_in[14];
    const float* W_uh  = (const float*)d_in[15]; const float* b_uh = (const float*)d_in[16];
    const float* W_out = (const float*)d_in[17]; const float* b_out = (const float*)d_in[18];

    const int N = in_sizes[0];

    float* out  = (float*)d_out;
    float* loss = out + (size_t)N * LBL;

    float* ws    = (float*)d_ws;
    float* ixx   = ws;
    float* fxx   = ixx + (size_t)N * HDIM;
    float* uxx   = fxx + (size_t)N * HDIM;
    float* c_all = uxx + (size_t)N * HDIM;
    float* h_all = c_all + (size_t)N * HDIM;

    int Nv = N;
    void* args[] = {
        (void*)&word_ids, (void*)&labels, (void*)&children_idx, (void*)&children_mask,
        (void*)&emb,
        (void*)&W_ix, (void*)&b_ix, (void*)&W_ih, (void*)&b_ih,
        (void*)&W_fx, (void*)&b_fx, (void*)&W_fh, (void*)&b_fh,
        (void*)&W_ux, (void*)&b_ux, (void*)&W_uh, (void*)&b_uh,
        (void*)&W_out, (void*)&b_out,
        (void*)&ixx, (void*)&fxx, (void*)&uxx, (void*)&c_all, (void*)&h_all,
        (void*)&out, (void*)&loss, (void*)&Nv
    };
    hipLaunchCooperativeKernel((const void*)tree_lstm_kernel,
                               dim3(NBLK), dim3(NTHR), args, 0, stream);
}

// Round 6
// 548.157 us; speedup vs baseline: 1.2321x; 1.1558x over previous
//
#include <hip/hip_runtime.h>
#include <math.h>

#define HDIM 300
#define KH   150
#define JP   150
#define LBL  5
#define NBLK 256
#define NTHR 1024

__device__ __forceinline__ float sigmoidf_(float x) {
    return 1.0f / (1.0f + expf(-x));
}

// agent-scope (cross-XCD coherent) data access for producer/consumer handoff
__device__ __forceinline__ void  gstore(float* p, float v) {
    __hip_atomic_store(p, v, __ATOMIC_RELAXED, __HIP_MEMORY_SCOPE_AGENT);
}
__device__ __forceinline__ float gload(const float* p) {
    return __hip_atomic_load(p, __ATOMIC_RELAXED, __HIP_MEMORY_SCOPE_AGENT);
}

// batched projection matvec: NS node-slots, thread = (mat g, K-half kh, colpair j2)
template<int NS>
__device__ __forceinline__ void proj_matvec(int g, int kh, int j2,
                                            const float xs[][HDIM],
                                            float2 pp[3][2][6][JP],
                                            const float* __restrict__ W)
{
    const float* __restrict__ Wp = W + (size_t)(kh * KH) * HDIM + 2 * j2;
    float2 acc[NS];
#pragma unroll
    for (int s = 0; s < NS; s++) acc[s] = make_float2(0.f, 0.f);
#pragma unroll 4
    for (int i = 0; i < KH; i++) {
        float2 w = *(const float2*)(Wp + (size_t)i * HDIM);
#pragma unroll
        for (int s = 0; s < NS; s++) {
            float xv = xs[s][kh * KH + i];
            acc[s].x = fmaf(xv, w.x, acc[s].x);
            acc[s].y = fmaf(xv, w.y, acc[s].y);
        }
    }
#pragma unroll
    for (int s = 0; s < NS; s++) pp[g][kh][s][j2] = acc[s];
}

// ---------------------------------------------------------------------------
// Flag-synchronized tree LSTM. Block b owns:
//   leaves 4b..4b+3           (if b < 128)  -> cells kept in LDS
//   internal nodes 512+2b, 513+2b          -> both on ONE level
// Level-1 parents (b<128) consume own leaves from LDS (no sync).
// Levels >=2 wait on the two children's per-node flags (agent-scope
// release/acquire); h/c handoff through agent-scope global stores/loads.
// No grid.sync anywhere. Out-head fused per block at the end.
// ---------------------------------------------------------------------------
__global__ __launch_bounds__(NTHR, 4)
void tree_lstm_kernel(const int* __restrict__ word_ids,
                      const int* __restrict__ labels,
                      const int* __restrict__ children_idx,
                      const int* __restrict__ children_mask,
                      const float* __restrict__ emb,
                      const float* __restrict__ W_ix, const float* __restrict__ b_ix,
                      const float* __restrict__ W_ih, const float* __restrict__ b_ih,
                      const float* __restrict__ W_fx, const float* __restrict__ b_fx,
                      const float* __restrict__ W_fh, const float* __restrict__ b_fh,
                      const float* __restrict__ W_ux, const float* __restrict__ b_ux,
                      const float* __restrict__ W_uh, const float* __restrict__ b_uh,
                      const float* __restrict__ W_out, const float* __restrict__ b_out,
                      float* __restrict__ c_all, float* __restrict__ h_all,
                      int* __restrict__ flags,
                      float* __restrict__ out, float* __restrict__ loss,
                      int N)
{
    __shared__ float  xs[6][HDIM];            // staged x rows
    __shared__ float2 pp[3][2][6][JP];        // proj K-half partials
    __shared__ float  proj[6][3][HDIM];       // ixx/fxx/uxx per owned node
    __shared__ float  leafh[4][HDIM], leafc[4][HDIM];
    __shared__ float  h0sA[HDIM], h1sA[HDIM], h0sB[HDIM], h1sB[HDIM];
    __shared__ float2 part[2][2][4][JP];      // [node][kh][q:aih,g0,g1,auh][j2]
    __shared__ float  hsave[2][HDIM];

    const int b   = blockIdx.x;
    const int tid = threadIdx.x;
    const int leaves = (N + 1) / 2;           // 512
    const int nInt   = N - leaves;            // 511
    const int kA = 2 * b, kB = 2 * b + 1;
    const int tA = leaves + kA;
    const bool hasB = (kB < nInt);
    const int tB = leaves + kB;
    const bool leafOwner = (b < leaves / 4);  // b < 128 <=> level-1 owner
    const int intSlot0 = leafOwner ? 4 : 0;

    // owned-node list
    int nodes[6]; int cnt;
    if (leafOwner) {
        nodes[0] = 4*b; nodes[1] = 4*b+1; nodes[2] = 4*b+2; nodes[3] = 4*b+3;
        nodes[4] = tA;  nodes[5] = tB;    cnt = 6;
    } else {
        nodes[0] = tA; cnt = 1;
        if (hasB) { nodes[1] = tB; cnt = 2; }
    }
    const int NS = leafOwner ? 6 : 2;

    // matvec thread mapping (3 groups x 5 waves; wave-uniform matrices)
    const int g   = tid / 320;
    const int rem = tid - g * 320;
    const bool act = (g < 3) && (rem < 2 * KH);
    const int kh  = rem / KH;
    const int j2  = rem - kh * KH;

    // ---------------- phase P: stage x, projections, leaf cells ----------------
    for (int idx = tid; idx < NS * HDIM; idx += NTHR) {
        int s = idx / HDIM, i = idx - s * HDIM;
        float v = 0.f;
        if (s < cnt) v = emb[(size_t)word_ids[nodes[s]] * HDIM + i];
        xs[s][i] = v;
    }
    __syncthreads();

    if (act) {
        const float* W = (g == 0) ? W_ix : (g == 1) ? W_fx : W_ux;
        if (leafOwner) proj_matvec<6>(g, kh, j2, xs, pp, W);
        else           proj_matvec<2>(g, kh, j2, xs, pp, W);
    }
    __syncthreads();

    if (tid < 3 * JP) {                       // combine K-halves + bias -> proj
        int gg = tid / JP, jj = tid - gg * JP;
        const float* B = (gg == 0) ? b_ix : (gg == 1) ? b_fx : b_ux;
        float2 bb = *(const float2*)(B + 2 * jj);
        for (int s = 0; s < cnt; s++) {
            float2 v;
            v.x = pp[gg][0][s][jj].x + pp[gg][1][s][jj].x + bb.x;
            v.y = pp[gg][0][s][jj].y + pp[gg][1][s][jj].y + bb.y;
            *(float2*)&proj[s][gg][2 * jj] = v;
        }
    }
    __syncthreads();

    if (leafOwner && tid < HDIM) {            // leaf cells (hsum = 0), stay in LDS
        const int j = tid;
        const float bih = b_ih[j], bfh = b_fh[j], buh = b_uh[j];
#pragma unroll
        for (int s = 0; s < 4; s++) {
            float ig = sigmoidf_(proj[s][0][j] + bih);
            float og = sigmoidf_(proj[s][1][j] + bfh);
            float ug = sigmoidf_(proj[s][2][j] + buh);
            float c = ig * ug;
            float h = og * tanhf(c);
            leafh[s][j] = h;
            leafc[s][j] = c;
        }
    }
    __syncthreads();

    // ---------------- level phase: wait children, 4 matvecs, cells ----------------
    if (!leafOwner) {                         // levels >= 2: poll children flags
        if (tid < 4) {
            int node = tid >> 1, ci = tid & 1;
            bool valid = node ? hasB : true;
            if (valid) {
                int t = node ? tB : tA;
                int kc = children_idx[2 * t + ci] - leaves;
                while (__hip_atomic_load(&flags[kc], __ATOMIC_ACQUIRE,
                                         __HIP_MEMORY_SCOPE_AGENT) == 0)
                    __builtin_amdgcn_s_sleep(2);
            }
        }
        __syncthreads();
    }

    // gather masked child h into LDS
    for (int idx = tid; idx < 4 * HDIM; idx += NTHR) {
        int vec = idx / HDIM, i = idx - vec * HDIM;
        int node = vec >> 1, ci = vec & 1;
        bool valid = node ? hasB : true;
        float v = 0.f;
        if (valid) {
            int t = node ? tB : tA;
            int ch = children_idx[2 * t + ci];
            float m = (float)children_mask[2 * t + ci];
            if (m != 0.f) {
                if (leafOwner) v = leafh[ch - 4 * b][i] * m;
                else           v = gload(&h_all[(size_t)ch * HDIM + i]) * m;
            }
        }
        float* dst = (vec == 0) ? h0sA : (vec == 1) ? h1sA : (vec == 2) ? h0sB : h1sB;
        dst[i] = v;
    }
    __syncthreads();

    if (act) {
        if (g == 1) {                         // W_fh: per-child accumulators, both nodes
            const float* __restrict__ Wp = W_fh + (size_t)(kh * KH) * HDIM + 2 * j2;
            float2 aA0 = {0,0}, aA1 = {0,0}, aB0 = {0,0}, aB1 = {0,0};
#pragma unroll 4
            for (int i = 0; i < KH; i++) {
                float2 w = *(const float2*)(Wp + (size_t)i * HDIM);
                float hA0 = h0sA[kh*KH+i], hA1 = h1sA[kh*KH+i];
                float hB0 = h0sB[kh*KH+i], hB1 = h1sB[kh*KH+i];
                aA0.x = fmaf(hA0, w.x, aA0.x); aA0.y = fmaf(hA0, w.y, aA0.y);
                aA1.x = fmaf(hA1, w.x, aA1.x); aA1.y = fmaf(hA1, w.y, aA1.y);
                aB0.x = fmaf(hB0, w.x, aB0.x); aB0.y = fmaf(hB0, w.y, aB0.y);
                aB1.x = fmaf(hB1, w.x, aB1.x); aB1.y = fmaf(hB1, w.y, aB1.y);
            }
            part[0][kh][1][j2] = aA0; part[0][kh][2][j2] = aA1;
            part[1][kh][1][j2] = aB0; part[1][kh][2][j2] = aB1;
        } else {                              // W_ih / W_uh on hsum, both nodes
            const float* W = (g == 0) ? W_ih : W_uh;
            const int q = (g == 0) ? 0 : 3;
            const float* __restrict__ Wp = W + (size_t)(kh * KH) * HDIM + 2 * j2;
            float2 aA = {0,0}, aB = {0,0};
#pragma unroll 4
            for (int i = 0; i < KH; i++) {
                float2 w = *(const float2*)(Wp + (size_t)i * HDIM);
                float hsA = h0sA[kh*KH+i] + h1sA[kh*KH+i];
                float hsB = h0sB[kh*KH+i] + h1sB[kh*KH+i];
                aA.x = fmaf(hsA, w.x, aA.x); aA.y = fmaf(hsA, w.y, aA.y);
                aB.x = fmaf(hsB, w.x, aB.x); aB.y = fmaf(hsB, w.y, aB.y);
            }
            part[0][kh][q][j2] = aA;
            part[1][kh][q][j2] = aB;
        }
    }
    __syncthreads();

    if (tid < 2 * HDIM) {                     // cell update for both nodes
        int node = tid / HDIM, j = tid - node * HDIM;
        bool valid = node ? hasB : true;
        if (valid) {
            int t = node ? tB : tA;
            int slot = intSlot0 + node;
            const float* P = (const float*)part;
            float aih = P[((node*2+0)*4+0)*HDIM + j] + P[((node*2+1)*4+0)*HDIM + j];
            float gg0 = P[((node*2+0)*4+1)*HDIM + j] + P[((node*2+1)*4+1)*HDIM + j];
            float gg1 = P[((node*2+0)*4+2)*HDIM + j] + P[((node*2+1)*4+2)*HDIM + j];
            float auh = P[((node*2+0)*4+3)*HDIM + j] + P[((node*2+1)*4+3)*HDIM + j];
            float vix = proj[slot][0][j], vfx = proj[slot][1][j], vux = proj[slot][2][j];
            float bfh = b_fh[j];
            float ig = sigmoidf_(vix + aih + b_ih[j]);
            float og = sigmoidf_(vfx + gg0 + gg1 + bfh);
            float ug = sigmoidf_(vux + auh + b_uh[j]);
            float f0 = sigmoidf_(gg0 + bfh + vfx);
            float f1 = sigmoidf_(gg1 + bfh + vfx);
            int c0 = children_idx[2 * t];
            int c1 = children_idx[2 * t + 1];
            float m0 = (float)children_mask[2 * t];
            float m1 = (float)children_mask[2 * t + 1];
            float cc0, cc1;
            if (leafOwner) {
                cc0 = leafc[c0 - 4 * b][j] * m0;
                cc1 = leafc[c1 - 4 * b][j] * m1;
            } else {
                cc0 = (m0 != 0.f) ? gload(&c_all[(size_t)c0 * HDIM + j]) * m0 : 0.f;
                cc1 = (m1 != 0.f) ? gload(&c_all[(size_t)c1 * HDIM + j]) * m1 : 0.f;
            }
            float c = ig * ug + f0 * cc0 + f1 * cc1;
            float h = og * tanhf(c);
            hsave[node][j] = h;
            if (t != N - 1) {                 // root has no consumer
                gstore(&h_all[(size_t)t * HDIM + j], h);
                gstore(&c_all[(size_t)t * HDIM + j], c);
            }
        }
    }
    __syncthreads();                          // all h/c stores drained (vmcnt 0)

    if (tid < 2) {                            // release flags
        int node = tid;
        bool valid = node ? hasB : true;
        if (valid) {
            int t = node ? tB : tA;
            if (t != N - 1)
                __hip_atomic_store(&flags[t - leaves], 1, __ATOMIC_RELEASE,
                                   __HIP_MEMORY_SCOPE_AGENT);
        }
    }

    // ---------------- out-head for all owned nodes ----------------
    {
        const int wv = tid >> 6, lane = tid & 63;
        const int nOut = (leafOwner ? 4 : 0) + 1 + (hasB ? 1 : 0);
        if (wv < nOut) {
            const float* hp; int t;
            if (leafOwner) {
                if (wv < 4) { hp = leafh[wv]; t = 4 * b + wv; }
                else        { hp = hsave[wv - 4]; t = (wv - 4) ? tB : tA; }
            } else {
                hp = hsave[wv]; t = wv ? tB : tA;
            }
            float acc[LBL];
#pragma unroll
            for (int k = 0; k < LBL; k++) acc[k] = 0.f;
            for (int i = lane; i < HDIM; i += 64) {
                float hv = hp[i];
#pragma unroll
                for (int k = 0; k < LBL; k++)
                    acc[k] = fmaf(hv, W_out[i * LBL + k], acc[k]);
            }
#pragma unroll
            for (int k = 0; k < LBL; k++) {
                float v = acc[k];
                for (int off = 32; off > 0; off >>= 1)
                    v += __shfl_down(v, off, 64);
                acc[k] = v;
            }
            if (lane == 0) {
                float lg[LBL];
                float mx = -1e30f;
#pragma unroll
                for (int k = 0; k < LBL; k++) {
                    lg[k] = acc[k] + b_out[k];
                    mx = fmaxf(mx, lg[k]);
                }
                float s = 0.f;
#pragma unroll
                for (int k = 0; k < LBL; k++) s += expf(lg[k] - mx);
                float lse = mx + logf(s);
                int lab = labels[t];
#pragma unroll
                for (int k = 0; k < LBL; k++)
                    out[t * LBL + k] = lg[k] - lse;
                atomicAdd(loss, -(lg[lab] - lse));
            }
        }
    }
}

// ---------------------------------------------------------------------------
extern "C" void kernel_launch(void* const* d_in, const int* in_sizes, int n_in,
                              void* d_out, int out_size, void* d_ws, size_t ws_size,
                              hipStream_t stream)
{
    const int*   word_ids      = (const int*)d_in[0];
    const int*   labels        = (const int*)d_in[1];
    const int*   children_idx  = (const int*)d_in[2];
    const int*   children_mask = (const int*)d_in[3];
    const float* emb   = (const float*)d_in[4];
    const float* W_ix  = (const float*)d_in[5];  const float* b_ix = (const float*)d_in[6];
    const float* W_ih  = (const float*)d_in[7];  const float* b_ih = (const float*)d_in[8];
    const float* W_fx  = (const float*)d_in[9];  const float* b_fx = (const float*)d_in[10];
    const float* W_fh  = (const float*)d_in[11]; const float* b_fh = (const float*)d_in[12];
    const float* W_ux  = (const float*)d_in[13]; const float* b_ux = (const float*)d_in[14];
    const float* W_uh  = (const float*)d_in[15]; const float* b_uh = (const float*)d_in[16];
    const float* W_out = (const float*)d_in[17]; const float* b_out = (const float*)d_in[18];

    const int N = in_sizes[0];

    float* out  = (float*)d_out;
    float* loss = out + (size_t)N * LBL;

    int*   flags = (int*)d_ws;                       // 512 ints
    float* c_all = (float*)d_ws + 512;
    float* h_all = c_all + (size_t)N * HDIM;

    hipMemsetAsync(flags, 0, 512 * sizeof(int), stream);
    hipMemsetAsync(loss, 0, sizeof(float), stream);

    int Nv = N;
    void* args[] = {
        (void*)&word_ids, (void*)&labels, (void*)&children_idx, (void*)&children_mask,
        (void*)&emb,
        (void*)&W_ix, (void*)&b_ix, (void*)&W_ih, (void*)&b_ih,
        (void*)&W_fx, (void*)&b_fx, (void*)&W_fh, (void*)&b_fh,
        (void*)&W_ux, (void*)&b_ux, (void*)&W_uh, (void*)&b_uh,
        (void*)&W_out, (void*)&b_out,
        (void*)&c_all, (void*)&h_all, (void*)&flags,
        (void*)&out, (void*)&loss, (void*)&Nv
    };
    hipLaunchCooperativeKernel((const void*)tree_lstm_kernel,
                               dim3(NBLK), dim3(NTHR), args, 0, stream);
}

// Round 7
// 466.951 us; speedup vs baseline: 1.4463x; 1.1739x over previous
//
#include <hip/hip_runtime.h>
#include <math.h>

#define HDIM 300
#define KH   150
#define JP   150
#define LBL  5
#define NBLK 256
#define NTHR 1024

__device__ __forceinline__ float sigmoidf_(float x) {
    return 1.0f / (1.0f + expf(-x));
}

// agent-scope (cross-XCD coherent, cache-bypassing) data access
__device__ __forceinline__ void  gstore(float* p, float v) {
    __hip_atomic_store(p, v, __ATOMIC_RELAXED, __HIP_MEMORY_SCOPE_AGENT);
}
__device__ __forceinline__ float gload(const float* p) {
    return __hip_atomic_load(p, __ATOMIC_RELAXED, __HIP_MEMORY_SCOPE_AGENT);
}

template<int NS>
__device__ __forceinline__ void proj_matvec(int g, int kh, int j2,
                                            const float xs[][HDIM],
                                            float2 pp[3][2][6][JP],
                                            const float* __restrict__ W)
{
    const float* __restrict__ Wp = W + (size_t)(kh * KH) * HDIM + 2 * j2;
    float2 acc[NS];
#pragma unroll
    for (int s = 0; s < NS; s++) acc[s] = make_float2(0.f, 0.f);
#pragma unroll 4
    for (int i = 0; i < KH; i++) {
        float2 w = *(const float2*)(Wp + (size_t)i * HDIM);
#pragma unroll
        for (int s = 0; s < NS; s++) {
            float xv = xs[s][kh * KH + i];
            acc[s].x = fmaf(xv, w.x, acc[s].x);
            acc[s].y = fmaf(xv, w.y, acc[s].y);
        }
    }
#pragma unroll
    for (int s = 0; s < NS; s++) pp[g][kh][s][j2] = acc[s];
}

// ---------------------------------------------------------------------------
// Flag-synchronized tree LSTM (see R6). Only change vs R6: the child-flag
// poll uses RELAXED agent loads (no per-iteration acquire -> no L1/L2
// invalidation storm). Data handoff is already via cache-bypassing
// agent-scope relaxed loads/stores, so no acquire is needed for visibility.
// ---------------------------------------------------------------------------
__global__ __launch_bounds__(NTHR, 4)
void tree_lstm_kernel(const int* __restrict__ word_ids,
                      const int* __restrict__ labels,
                      const int* __restrict__ children_idx,
                      const int* __restrict__ children_mask,
                      const float* __restrict__ emb,
                      const float* __restrict__ W_ix, const float* __restrict__ b_ix,
                      const float* __restrict__ W_ih, const float* __restrict__ b_ih,
                      const float* __restrict__ W_fx, const float* __restrict__ b_fx,
                      const float* __restrict__ W_fh, const float* __restrict__ b_fh,
                      const float* __restrict__ W_ux, const float* __restrict__ b_ux,
                      const float* __restrict__ W_uh, const float* __restrict__ b_uh,
                      const float* __restrict__ W_out, const float* __restrict__ b_out,
                      float* __restrict__ c_all, float* __restrict__ h_all,
                      int* __restrict__ flags,
                      float* __restrict__ out, float* __restrict__ loss,
                      int N)
{
    __shared__ float  xs[6][HDIM];
    __shared__ float2 pp[3][2][6][JP];
    __shared__ float  proj[6][3][HDIM];
    __shared__ float  leafh[4][HDIM], leafc[4][HDIM];
    __shared__ float  h0sA[HDIM], h1sA[HDIM], h0sB[HDIM], h1sB[HDIM];
    __shared__ float2 part[2][2][4][JP];
    __shared__ float  hsave[2][HDIM];

    const int b   = blockIdx.x;
    const int tid = threadIdx.x;
    const int leaves = (N + 1) / 2;           // 512
    const int nInt   = N - leaves;            // 511
    const int kA = 2 * b, kB = 2 * b + 1;
    const int tA = leaves + kA;
    const bool hasB = (kB < nInt);
    const int tB = leaves + kB;
    const bool leafOwner = (b < leaves / 4);  // b < 128
    const int intSlot0 = leafOwner ? 4 : 0;

    int nodes[6]; int cnt;
    if (leafOwner) {
        nodes[0] = 4*b; nodes[1] = 4*b+1; nodes[2] = 4*b+2; nodes[3] = 4*b+3;
        nodes[4] = tA;  nodes[5] = tB;    cnt = 6;
    } else {
        nodes[0] = tA; cnt = 1;
        if (hasB) { nodes[1] = tB; cnt = 2; }
    }
    const int NS = leafOwner ? 6 : 2;

    const int g   = tid / 320;
    const int rem = tid - g * 320;
    const bool act = (g < 3) && (rem < 2 * KH);
    const int kh  = rem / KH;
    const int j2  = rem - kh * KH;

    // ---------------- phase P ----------------
    for (int idx = tid; idx < NS * HDIM; idx += NTHR) {
        int s = idx / HDIM, i = idx - s * HDIM;
        float v = 0.f;
        if (s < cnt) v = emb[(size_t)word_ids[nodes[s]] * HDIM + i];
        xs[s][i] = v;
    }
    __syncthreads();

    if (act) {
        const float* W = (g == 0) ? W_ix : (g == 1) ? W_fx : W_ux;
        if (leafOwner) proj_matvec<6>(g, kh, j2, xs, pp, W);
        else           proj_matvec<2>(g, kh, j2, xs, pp, W);
    }
    __syncthreads();

    if (tid < 3 * JP) {
        int gg = tid / JP, jj = tid - gg * JP;
        const float* B = (gg == 0) ? b_ix : (gg == 1) ? b_fx : b_ux;
        float2 bb = *(const float2*)(B + 2 * jj);
        for (int s = 0; s < cnt; s++) {
            float2 v;
            v.x = pp[gg][0][s][jj].x + pp[gg][1][s][jj].x + bb.x;
            v.y = pp[gg][0][s][jj].y + pp[gg][1][s][jj].y + bb.y;
            *(float2*)&proj[s][gg][2 * jj] = v;
        }
    }
    __syncthreads();

    if (leafOwner && tid < HDIM) {
        const int j = tid;
        const float bih = b_ih[j], bfh = b_fh[j], buh = b_uh[j];
#pragma unroll
        for (int s = 0; s < 4; s++) {
            float ig = sigmoidf_(proj[s][0][j] + bih);
            float og = sigmoidf_(proj[s][1][j] + bfh);
            float ug = sigmoidf_(proj[s][2][j] + buh);
            float c = ig * ug;
            float h = og * tanhf(c);
            leafh[s][j] = h;
            leafc[s][j] = c;
        }
    }
    __syncthreads();

    // ---------------- level phase ----------------
    if (!leafOwner) {
        if (tid < 4) {
            int node = tid >> 1, ci = tid & 1;
            bool valid = node ? hasB : true;
            if (valid) {
                int t = node ? tB : tA;
                int kc = children_idx[2 * t + ci] - leaves;
                // RELAXED poll: no per-iteration cache invalidation.
                while (__hip_atomic_load(&flags[kc], __ATOMIC_RELAXED,
                                         __HIP_MEMORY_SCOPE_AGENT) == 0)
                    __builtin_amdgcn_s_sleep(1);
            }
        }
        __syncthreads();
    }

    for (int idx = tid; idx < 4 * HDIM; idx += NTHR) {
        int vec = idx / HDIM, i = idx - vec * HDIM;
        int node = vec >> 1, ci = vec & 1;
        bool valid = node ? hasB : true;
        float v = 0.f;
        if (valid) {
            int t = node ? tB : tA;
            int ch = children_idx[2 * t + ci];
            float m = (float)children_mask[2 * t + ci];
            if (m != 0.f) {
                if (leafOwner) v = leafh[ch - 4 * b][i] * m;
                else           v = gload(&h_all[(size_t)ch * HDIM + i]) * m;
            }
        }
        float* dst = (vec == 0) ? h0sA : (vec == 1) ? h1sA : (vec == 2) ? h0sB : h1sB;
        dst[i] = v;
    }
    __syncthreads();

    if (act) {
        if (g == 1) {
            const float* __restrict__ Wp = W_fh + (size_t)(kh * KH) * HDIM + 2 * j2;
            float2 aA0 = {0,0}, aA1 = {0,0}, aB0 = {0,0}, aB1 = {0,0};
#pragma unroll 4
            for (int i = 0; i < KH; i++) {
                float2 w = *(const float2*)(Wp + (size_t)i * HDIM);
                float hA0 = h0sA[kh*KH+i], hA1 = h1sA[kh*KH+i];
                float hB0 = h0sB[kh*KH+i], hB1 = h1sB[kh*KH+i];
                aA0.x = fmaf(hA0, w.x, aA0.x); aA0.y = fmaf(hA0, w.y, aA0.y);
                aA1.x = fmaf(hA1, w.x, aA1.x); aA1.y = fmaf(hA1, w.y, aA1.y);
                aB0.x = fmaf(hB0, w.x, aB0.x); aB0.y = fmaf(hB0, w.y, aB0.y);
                aB1.x = fmaf(hB1, w.x, aB1.x); aB1.y = fmaf(hB1, w.y, aB1.y);
            }
            part[0][kh][1][j2] = aA0; part[0][kh][2][j2] = aA1;
            part[1][kh][1][j2] = aB0; part[1][kh][2][j2] = aB1;
        } else {
            const float* W = (g == 0) ? W_ih : W_uh;
            const int q = (g == 0) ? 0 : 3;
            const float* __restrict__ Wp = W + (size_t)(kh * KH) * HDIM + 2 * j2;
            float2 aA = {0,0}, aB = {0,0};
#pragma unroll 4
            for (int i = 0; i < KH; i++) {
                float2 w = *(const float2*)(Wp + (size_t)i * HDIM);
                float hsA = h0sA[kh*KH+i] + h1sA[kh*KH+i];
                float hsB = h0sB[kh*KH+i] + h1sB[kh*KH+i];
                aA.x = fmaf(hsA, w.x, aA.x); aA.y = fmaf(hsA, w.y, aA.y);
                aB.x = fmaf(hsB, w.x, aB.x); aB.y = fmaf(hsB, w.y, aB.y);
            }
            part[0][kh][q][j2] = aA;
            part[1][kh][q][j2] = aB;
        }
    }
    __syncthreads();

    if (tid < 2 * HDIM) {
        int node = tid / HDIM, j = tid - node * HDIM;
        bool valid = node ? hasB : true;
        if (valid) {
            int t = node ? tB : tA;
            int slot = intSlot0 + node;
            const float* P = (const float*)part;
            float aih = P[((node*2+0)*4+0)*HDIM + j] + P[((node*2+1)*4+0)*HDIM + j];
            float gg0 = P[((node*2+0)*4+1)*HDIM + j] + P[((node*2+1)*4+1)*HDIM + j];
            float gg1 = P[((node*2+0)*4+2)*HDIM + j] + P[((node*2+1)*4+2)*HDIM + j];
            float auh = P[((node*2+0)*4+3)*HDIM + j] + P[((node*2+1)*4+3)*HDIM + j];
            float vix = proj[slot][0][j], vfx = proj[slot][1][j], vux = proj[slot][2][j];
            float bfh = b_fh[j];
            float ig = sigmoidf_(vix + aih + b_ih[j]);
            float og = sigmoidf_(vfx + gg0 + gg1 + bfh);
            float ug = sigmoidf_(vux + auh + b_uh[j]);
            float f0 = sigmoidf_(gg0 + bfh + vfx);
            float f1 = sigmoidf_(gg1 + bfh + vfx);
            int c0 = children_idx[2 * t];
            int c1 = children_idx[2 * t + 1];
            float m0 = (float)children_mask[2 * t];
            float m1 = (float)children_mask[2 * t + 1];
            float cc0, cc1;
            if (leafOwner) {
                cc0 = leafc[c0 - 4 * b][j] * m0;
                cc1 = leafc[c1 - 4 * b][j] * m1;
            } else {
                cc0 = (m0 != 0.f) ? gload(&c_all[(size_t)c0 * HDIM + j]) * m0 : 0.f;
                cc1 = (m1 != 0.f) ? gload(&c_all[(size_t)c1 * HDIM + j]) * m1 : 0.f;
            }
            float c = ig * ug + f0 * cc0 + f1 * cc1;
            float h = og * tanhf(c);
            hsave[node][j] = h;
            if (t != N - 1) {
                gstore(&h_all[(size_t)t * HDIM + j], h);
                gstore(&c_all[(size_t)t * HDIM + j], c);
            }
        }
    }
    __syncthreads();                          // drains vmcnt: data at L3 before flags

    if (tid < 2) {
        int node = tid;
        bool valid = node ? hasB : true;
        if (valid) {
            int t = node ? tB : tA;
            if (t != N - 1)
                __hip_atomic_store(&flags[t - leaves], 1, __ATOMIC_RELEASE,
                                   __HIP_MEMORY_SCOPE_AGENT);
        }
    }

    // ---------------- out-head ----------------
    {
        const int wv = tid >> 6, lane = tid & 63;
        const int nOut = (leafOwner ? 4 : 0) + 1 + (hasB ? 1 : 0);
        if (wv < nOut) {
            const float* hp; int t;
            if (leafOwner) {
                if (wv < 4) { hp = leafh[wv]; t = 4 * b + wv; }
                else        { hp = hsave[wv - 4]; t = (wv - 4) ? tB : tA; }
            } else {
                hp = hsave[wv]; t = wv ? tB : tA;
            }
            float acc[LBL];
#pragma unroll
            for (int k = 0; k < LBL; k++) acc[k] = 0.f;
            for (int i = lane; i < HDIM; i += 64) {
                float hv = hp[i];
#pragma unroll
                for (int k = 0; k < LBL; k++)
                    acc[k] = fmaf(hv, W_out[i * LBL + k], acc[k]);
            }
#pragma unroll
            for (int k = 0; k < LBL; k++) {
                float v = acc[k];
                for (int off = 32; off > 0; off >>= 1)
                    v += __shfl_down(v, off, 64);
                acc[k] = v;
            }
            if (lane == 0) {
                float lg[LBL];
                float mx = -1e30f;
#pragma unroll
                for (int k = 0; k < LBL; k++) {
                    lg[k] = acc[k] + b_out[k];
                    mx = fmaxf(mx, lg[k]);
                }
                float s = 0.f;
#pragma unroll
                for (int k = 0; k < LBL; k++) s += expf(lg[k] - mx);
                float lse = mx + logf(s);
                int lab = labels[t];
#pragma unroll
                for (int k = 0; k < LBL; k++)
                    out[t * LBL + k] = lg[k] - lse;
                atomicAdd(loss, -(lg[lab] - lse));
            }
        }
    }
}

// ---------------------------------------------------------------------------
extern "C" void kernel_launch(void* const* d_in, const int* in_sizes, int n_in,
                              void* d_out, int out_size, void* d_ws, size_t ws_size,
                              hipStream_t stream)
{
    const int*   word_ids      = (const int*)d_in[0];
    const int*   labels        = (const int*)d_in[1];
    const int*   children_idx  = (const int*)d_in[2];
    const int*   children_mask = (const int*)d_in[3];
    const float* emb   = (const float*)d_in[4];
    const float* W_ix  = (const float*)d_in[5];  const float* b_ix = (const float*)d_in[6];
    const float* W_ih  = (const float*)d_in[7];  const float* b_ih = (const float*)d_in[8];
    const float* W_fx  = (const float*)d_in[9];  const float* b_fx = (const float*)d_in[10];
    const float* W_fh  = (const float*)d_in[11]; const float* b_fh = (const float*)d_in[12];
    const float* W_ux  = (const float*)d_in[13]; const float* b_ux = (const float*)d_in[14];
    const float* W_uh  = (const float*)d_in[15]; const float* b_uh = (const float*)d_in[16];
    const float* W_out = (const float*)d_in[17]; const float* b_out = (const float*)d_in[18];

    const int N = in_sizes[0];

    float* out  = (float*)d_out;
    float* loss = out + (size_t)N * LBL;

    int*   flags = (int*)d_ws;                       // 512 ints
    float* c_all = (float*)d_ws + 512;
    float* h_all = c_all + (size_t)N * HDIM;

    hipMemsetAsync(flags, 0, 512 * sizeof(int), stream);
    hipMemsetAsync(loss, 0, sizeof(float), stream);

    int Nv = N;
    void* args[] = {
        (void*)&word_ids, (void*)&labels, (void*)&children_idx, (void*)&children_mask,
        (void*)&emb,
        (void*)&W_ix, (void*)&b_ix, (void*)&W_ih, (void*)&b_ih,
        (void*)&W_fx, (void*)&b_fx, (void*)&W_fh, (void*)&b_fh,
        (void*)&W_ux, (void*)&b_ux, (void*)&W_uh, (void*)&b_uh,
        (void*)&W_out, (void*)&b_out,
        (void*)&c_all, (void*)&h_all, (void*)&flags,
        (void*)&out, (void*)&loss, (void*)&Nv
    };
    hipLaunchCooperativeKernel((const void*)tree_lstm_kernel,
                               dim3(NBLK), dim3(NTHR), args, 0, stream);
}

// Round 8
// 416.434 us; speedup vs baseline: 1.6218x; 1.1213x over previous
//
#include <hip/hip_runtime.h>
#include <math.h>

#define HDIM 300
#define CW   30          // colgroup width
#define NCG  10          // colgroups (NCG*CW == HDIM)
#define NREP 25          // replicas
#define NBLK (NCG*NREP)  // 250 blocks
#define NTHR 1024
#define LBL  5
#define HPAD 301         // LDS row pad (bank-conflict-free for 16 slots)
#define MAXI 21          // max owned internal nodes per replica (N=1023)

__device__ __forceinline__ float sigmoidf_(float x) {
    return 1.0f / (1.0f + expf(-x));
}
// agent-scope (cross-XCD coherent, L2-bypassing) handoff
__device__ __forceinline__ void  gstore(float* p, float v) {
    __hip_atomic_store(p, v, __ATOMIC_RELAXED, __HIP_MEMORY_SCOPE_AGENT);
}
__device__ __forceinline__ float gload(const float* p) {
    return __hip_atomic_load(p, __ATOMIC_RELAXED, __HIP_MEMORY_SCOPE_AGENT);
}

// ---------------------------------------------------------------------------
// Persistent-weight column-split tree LSTM.
// Block b: replica r=b/NCG, colgroup cg=b%NCG (cols [cg*CW, cg*CW+CW)).
// Owns (node t, colgroup cg) tasks for all t with t%NREP==r:
//   proj slice (x-weights in LDS), leaf cell, level cell (h-weights in LDS),
//   and out-head for t with (t/NREP)%NCG==cg.
// Per-node completion counter flags[t] (10 bumps). Poll relaxed; bump after
// vmcnt-draining __syncthreads (R6/R7-validated protocol).
// ---------------------------------------------------------------------------
__global__ __launch_bounds__(NTHR)
void tree_lstm_kernel(const int* __restrict__ word_ids,
                      const int* __restrict__ labels,
                      const int* __restrict__ children_idx,
                      const int* __restrict__ children_mask,
                      const float* __restrict__ emb,
                      const float* __restrict__ W_ix, const float* __restrict__ b_ix,
                      const float* __restrict__ W_ih, const float* __restrict__ b_ih,
                      const float* __restrict__ W_fx, const float* __restrict__ b_fx,
                      const float* __restrict__ W_fh, const float* __restrict__ b_fh,
                      const float* __restrict__ W_ux, const float* __restrict__ b_ux,
                      const float* __restrict__ W_uh, const float* __restrict__ b_uh,
                      const float* __restrict__ W_out, const float* __restrict__ b_out,
                      float* __restrict__ c_all, float* __restrict__ h_all,
                      int* __restrict__ flags,
                      float* __restrict__ out, float* __restrict__ loss,
                      int N)
{
    __shared__ float wlds[3][HDIM][CW];    // 108 KB persistent weight slices
    __shared__ float hstf[16 * HPAD];      // x-stage (16 slots) / h-stage (8 nodes x 2)
    __shared__ float cst[2][8][CW];        // child c slices
    __shared__ float partf[3840];          // K-split partials
    __shared__ float prj[3][MAXI][CW];     // internal-node proj slices
    __shared__ float bsl[6][CW];           // bias slices: ih,fh,uh,ix,fx,ux
    __shared__ int   meta_ci[8][2];
    __shared__ float meta_m[8][2];

    const int b   = blockIdx.x;
    const int tid = threadIdx.x;
    const int r   = b / NCG;
    const int cg  = b - r * NCG;
    const int c0  = cg * CW;
    const int leaves = (N + 1) / 2;                     // 512
    const int cntOwn   = (N - 1 - r) / NREP + 1;        // owned nodes
    const int j0int    = ((r - leaves) % NREP + NREP) % NREP;
    const int t0int    = leaves + j0int;                // first owned internal t

    // ---------------- phase A: stage x-weights + bias slices ----------------
    for (int idx = tid; idx < 3 * HDIM * CW; idx += NTHR) {
        int m = idx / (HDIM * CW), rem = idx - m * (HDIM * CW);
        int k = rem / CW, cc = rem - k * CW;
        const float* W = (m == 0) ? W_ix : (m == 1) ? W_fx : W_ux;
        wlds[m][k][cc] = W[(size_t)k * HDIM + c0 + cc];
    }
    if (tid < 6 * CW) {
        int m = tid / CW, cc = tid - m * CW;
        const float* B = (m == 0) ? b_ih : (m == 1) ? b_fh : (m == 2) ? b_uh
                       : (m == 3) ? b_ix : (m == 4) ? b_fx : b_ux;
        bsl[m][cc] = B[c0 + cc];
    }
    __syncthreads();

    // ---------------- phase B: projections (+ leaf cells) in 16-node batches ----------------
    for (int b0 = 0; b0 < cntOwn; b0 += 16) {
        for (int idx = tid; idx < 16 * HDIM; idx += NTHR) {   // stage x rows
            int s = idx / HDIM, k = idx - s * HDIM;
            int oi = b0 + s;
            float v = 0.f;
            if (oi < cntOwn) {
                int t = r + NREP * oi;
                v = emb[(size_t)word_ids[t] * HDIM + k];
            }
            hstf[s * HPAD + k] = v;
        }
        __syncthreads();

        if (tid < 960) {                                      // 3-matrix matvec, K-halves
            int s = tid & 15, cc = (tid >> 4) % CW, k2 = tid / 480;
            int kb = k2 * 150;
            float a0 = 0.f, a1 = 0.f, a2 = 0.f;
            for (int i = 0; i < 150; i++) {
                int k = kb + i;
                float xv = hstf[s * HPAD + k];
                a0 = fmaf(xv, wlds[0][k][cc], a0);
                a1 = fmaf(xv, wlds[1][k][cc], a1);
                a2 = fmaf(xv, wlds[2][k][cc], a2);
            }
            partf[((0 * 2 + k2) * 16 + s) * CW + cc] = a0;
            partf[((1 * 2 + k2) * 16 + s) * CW + cc] = a1;
            partf[((2 * 2 + k2) * 16 + s) * CW + cc] = a2;
        }
        __syncthreads();

        if (tid < 480) {                                      // combine; leaf cell or stash
            int s = tid / CW, cc = tid - (tid / CW) * CW;
            int oi = b0 + s;
            if (oi < cntOwn) {
                int t = r + NREP * oi;
                float vix = partf[(0 * 16 + s) * CW + cc] + partf[(1 * 16 + s) * CW + cc] + bsl[3][cc];
                float vfx = partf[(2 * 16 + s) * CW + cc] + partf[(3 * 16 + s) * CW + cc] + bsl[4][cc];
                float vux = partf[(4 * 16 + s) * CW + cc] + partf[(5 * 16 + s) * CW + cc] + bsl[5][cc];
                if (t < leaves) {
                    float ig = sigmoidf_(vix + bsl[0][cc]);
                    float og = sigmoidf_(vfx + bsl[1][cc]);
                    float ug = sigmoidf_(vux + bsl[2][cc]);
                    float cv = ig * ug;
                    float hv = og * tanhf(cv);
                    gstore(&h_all[(size_t)t * HDIM + c0 + cc], hv);
                    gstore(&c_all[(size_t)t * HDIM + c0 + cc], cv);
                } else {
                    int ii = (t - t0int) / NREP;
                    prj[0][ii][cc] = vix;
                    prj[1][ii][cc] = vfx;
                    prj[2][ii][cc] = vux;
                }
            }
        }
        __syncthreads();                                      // drain stores (vmcnt 0)

        if (tid < 16) {                                       // leaf counters
            int oi = b0 + tid;
            if (oi < cntOwn) {
                int t = r + NREP * oi;
                if (t < leaves)
                    __hip_atomic_fetch_add(&flags[t], 1, __ATOMIC_RELAXED,
                                           __HIP_MEMORY_SCOPE_AGENT);
            }
        }
        __syncthreads();
    }

    // ---------------- phase C: restage recurrent weights ----------------
    for (int idx = tid; idx < 3 * HDIM * CW; idx += NTHR) {
        int m = idx / (HDIM * CW), rem = idx - m * (HDIM * CW);
        int k = rem / CW, cc = rem - k * CW;
        const float* W = (m == 0) ? W_ih : (m == 1) ? W_fh : W_uh;
        wlds[m][k][cc] = W[(size_t)k * HDIM + c0 + cc];
    }
    __syncthreads();

    // ---------------- phase D: levels (8-node batches, per-level so no intra-batch deps) ----------------
    int start = leaves, size = leaves / 2;
    while (size >= 1) {
        int j0 = ((r - start) % NREP + NREP) % NREP;
        int nOwn = (j0 < size) ? ((size - 1 - j0) / NREP + 1) : 0;
        for (int b0 = 0; b0 < nOwn; b0 += 8) {
            if (tid < 16) {                                   // meta
                int s = tid >> 1, ci = tid & 1;
                int oi = b0 + s;
                int cidx = 0; float mv = 0.f;
                if (oi < nOwn) {
                    int t = start + j0 + NREP * oi;
                    cidx = children_idx[2 * t + ci];
                    mv = (float)children_mask[2 * t + ci];
                }
                meta_ci[s][ci] = cidx;
                meta_m[s][ci]  = mv;
            }
            __syncthreads();

            if (tid < 16) {                                   // poll children counters
                int s = tid >> 1, ci = tid & 1;
                if (b0 + s < nOwn && meta_m[s][ci] != 0.f) {
                    while (__hip_atomic_load(&flags[meta_ci[s][ci]], __ATOMIC_RELAXED,
                                             __HIP_MEMORY_SCOPE_AGENT) < NCG)
                        __builtin_amdgcn_s_sleep(1);
                }
            }
            __syncthreads();

            for (int idx = tid; idx < 16 * HDIM; idx += NTHR) {   // gather child h (full)
                int sl = idx / HDIM, k = idx - sl * HDIM;
                int s = sl >> 1, ci = sl & 1;
                float v = 0.f;
                if (b0 + s < nOwn) {
                    float m = meta_m[s][ci];
                    if (m != 0.f)
                        v = gload(&h_all[(size_t)meta_ci[s][ci] * HDIM + k]) * m;
                }
                hstf[sl * HPAD + k] = v;
            }
            for (int idx = tid; idx < 2 * 8 * CW; idx += NTHR) {  // gather child c slices
                int ci = idx / (8 * CW), rem2 = idx - ci * 8 * CW;
                int s = rem2 / CW, cc = rem2 - s * CW;
                float v = 0.f;
                if (b0 + s < nOwn) {
                    float m = meta_m[s][ci];
                    if (m != 0.f)
                        v = gload(&c_all[(size_t)meta_ci[s][ci] * HDIM + c0 + cc]) * m;
                }
                cst[ci][s][cc] = v;
            }
            __syncthreads();

            if (tid < 960) {                                  // recurrent matvec (K quarters)
                int s = tid & 7, cc = (tid >> 3) % CW, kc = tid / 240;
                int kb = kc * 75;
                float aih = 0.f, af0 = 0.f, af1 = 0.f, auh = 0.f;
                for (int i = 0; i < 75; i++) {
                    int k = kb + i;
                    float h0 = hstf[(2 * s) * HPAD + k];
                    float h1 = hstf[(2 * s + 1) * HPAD + k];
                    float hs = h0 + h1;
                    float wi = wlds[0][k][cc];
                    float wf = wlds[1][k][cc];
                    float wu = wlds[2][k][cc];
                    aih = fmaf(hs, wi, aih);
                    af0 = fmaf(h0, wf, af0);
                    af1 = fmaf(h1, wf, af1);
                    auh = fmaf(hs, wu, auh);
                }
                partf[((0 * 4 + kc) * 8 + s) * CW + cc] = aih;
                partf[((1 * 4 + kc) * 8 + s) * CW + cc] = af0;
                partf[((2 * 4 + kc) * 8 + s) * CW + cc] = af1;
                partf[((3 * 4 + kc) * 8 + s) * CW + cc] = auh;
            }
            __syncthreads();

            if (tid < 240) {                                  // reduce + cell
                int s = tid / CW, cc = tid - (tid / CW) * CW;
                int oi = b0 + s;
                if (oi < nOwn) {
                    int t = start + j0 + NREP * oi;
                    float aih = 0.f, g0 = 0.f, g1 = 0.f, auh = 0.f;
#pragma unroll
                    for (int kc = 0; kc < 4; kc++) {
                        aih += partf[((0 * 4 + kc) * 8 + s) * CW + cc];
                        g0  += partf[((1 * 4 + kc) * 8 + s) * CW + cc];
                        g1  += partf[((2 * 4 + kc) * 8 + s) * CW + cc];
                        auh += partf[((3 * 4 + kc) * 8 + s) * CW + cc];
                    }
                    int ii = (t - t0int) / NREP;
                    float vix = prj[0][ii][cc], vfx = prj[1][ii][cc], vux = prj[2][ii][cc];
                    float bfh = bsl[1][cc];
                    float ig = sigmoidf_(vix + aih + bsl[0][cc]);
                    float og = sigmoidf_(vfx + g0 + g1 + bfh);
                    float ug = sigmoidf_(vux + auh + bsl[2][cc]);
                    float f0 = sigmoidf_(g0 + bfh + vfx);
                    float f1 = sigmoidf_(g1 + bfh + vfx);
                    float cv = ig * ug + f0 * cst[0][s][cc] + f1 * cst[1][s][cc];
                    float hv = og * tanhf(cv);
                    gstore(&h_all[(size_t)t * HDIM + c0 + cc], hv);
                    gstore(&c_all[(size_t)t * HDIM + c0 + cc], cv);
                }
            }
            __syncthreads();                                  // drain stores

            if (tid < 8 && b0 + tid < nOwn) {                 // bump node counters
                int t = start + j0 + NREP * (b0 + tid);
                __hip_atomic_fetch_add(&flags[t], 1, __ATOMIC_RELAXED,
                                       __HIP_MEMORY_SCOPE_AGENT);
            }
            __syncthreads();
        }
        start += size;
        size >>= 1;
    }

    // ---------------- phase E: out-head (wave-per-node, poll completion) ----------------
    {
        const int w = tid >> 6, lane = tid & 63;
        for (int oi = cg + NCG * w; oi < cntOwn; oi += NCG * 16) {
            int t = r + NREP * oi;
            while (__hip_atomic_load(&flags[t], __ATOMIC_RELAXED,
                                     __HIP_MEMORY_SCOPE_AGENT) < NCG)
                __builtin_amdgcn_s_sleep(8);
            float acc[LBL];
#pragma unroll
            for (int q = 0; q < LBL; q++) acc[q] = 0.f;
            for (int k = lane; k < HDIM; k += 64) {
                float hv = gload(&h_all[(size_t)t * HDIM + k]);
#pragma unroll
                for (int q = 0; q < LBL; q++)
                    acc[q] = fmaf(hv, W_out[k * LBL + q], acc[q]);
            }
#pragma unroll
            for (int q = 0; q < LBL; q++) {
                float v = acc[q];
                for (int off = 32; off > 0; off >>= 1)
                    v += __shfl_down(v, off, 64);
                acc[q] = v;
            }
            if (lane == 0) {
                float lg[LBL];
                float mx = -1e30f;
#pragma unroll
                for (int q = 0; q < LBL; q++) {
                    lg[q] = acc[q] + b_out[q];
                    mx = fmaxf(mx, lg[q]);
                }
                float s = 0.f;
#pragma unroll
                for (int q = 0; q < LBL; q++) s += expf(lg[q] - mx);
                float lse = mx + logf(s);
                int lab = labels[t];
#pragma unroll
                for (int q = 0; q < LBL; q++)
                    out[t * LBL + q] = lg[q] - lse;
                atomicAdd(loss, -(lg[lab] - lse));
            }
        }
    }
}

// ---------------------------------------------------------------------------
extern "C" void kernel_launch(void* const* d_in, const int* in_sizes, int n_in,
                              void* d_out, int out_size, void* d_ws, size_t ws_size,
                              hipStream_t stream)
{
    const int*   word_ids      = (const int*)d_in[0];
    const int*   labels        = (const int*)d_in[1];
    const int*   children_idx  = (const int*)d_in[2];
    const int*   children_mask = (const int*)d_in[3];
    const float* emb   = (const float*)d_in[4];
    const float* W_ix  = (const float*)d_in[5];  const float* b_ix = (const float*)d_in[6];
    const float* W_ih  = (const float*)d_in[7];  const float* b_ih = (const float*)d_in[8];
    const float* W_fx  = (const float*)d_in[9];  const float* b_fx = (const float*)d_in[10];
    const float* W_fh  = (const float*)d_in[11]; const float* b_fh = (const float*)d_in[12];
    const float* W_ux  = (const float*)d_in[13]; const float* b_ux = (const float*)d_in[14];
    const float* W_uh  = (const float*)d_in[15]; const float* b_uh = (const float*)d_in[16];
    const float* W_out = (const float*)d_in[17]; const float* b_out = (const float*)d_in[18];

    const int N = in_sizes[0];

    float* out  = (float*)d_out;
    float* loss = out + (size_t)N * LBL;

    int*   flags = (int*)d_ws;                       // N counters (round up 1024)
    float* c_all = (float*)d_ws + 1024;
    float* h_all = c_all + (size_t)N * HDIM;

    hipMemsetAsync(flags, 0, 1024 * sizeof(int), stream);
    hipMemsetAsync(loss, 0, sizeof(float), stream);

    int Nv = N;
    void* args[] = {
        (void*)&word_ids, (void*)&labels, (void*)&children_idx, (void*)&children_mask,
        (void*)&emb,
        (void*)&W_ix, (void*)&b_ix, (void*)&W_ih, (void*)&b_ih,
        (void*)&W_fx, (void*)&b_fx, (void*)&W_fh, (void*)&b_fh,
        (void*)&W_ux, (void*)&b_ux, (void*)&W_uh, (void*)&b_uh,
        (void*)&W_out, (void*)&b_out,
        (void*)&c_all, (void*)&h_all, (void*)&flags,
        (void*)&out, (void*)&loss, (void*)&Nv
    };
    hipLaunchCooperativeKernel((const void*)tree_lstm_kernel,
                               dim3(NBLK), dim3(NTHR), args, 0, stream);
}